// Round 13
// baseline (112.854 us; speedup 1.0000x reference)
//
#include <hip/hip_runtime.h>

#define PI_D 3.14159265358979323846
#define PI_F 3.14159265358979323846f

// ---- workspace layout (floats) ----
// V01 @ 2359296  : 524288    V02 @ 2883584 : 262144    V12 @ 3145728 : 131072
// P1p @ 3276800  : 128       P2p @ 3276928 : 64

__device__ inline float rtab_val(int n, int m2, int t) {
  if (t == 0) return 1.0f;
  double th = PI_D * (double)t / (double)n;
  double v = sin(th * (double)(m2 - 1)) / sin(th) + cos(th * (double)m2);
  return (float)(v / (double)m2);  // 1/m2 per axis
}

// Fused front kernel: P partials, V pass, out zeroing. (proven R11 code)
__global__ __launch_bounds__(256) void k_front(const float* __restrict__ X1,
                                               const float* __restrict__ X2,
                                               float* __restrict__ P1p,
                                               float* __restrict__ P2p,
                                               float* __restrict__ V01,
                                               float* __restrict__ V02,
                                               float* __restrict__ V12,
                                               float* __restrict__ out) {
  int bid = blockIdx.x;
  int t = threadIdx.x;
  if (bid == 448) {
    for (int i = t; i < 5376; i += 256) out[i] = 0.f;
    return;
  }
  if (bid < 192) {
    const float* X; float* P; int lg, nsp, idx0;
    if (bid < 128) { X = X1; P = P1p; lg = 7; nsp = 8; idx0 = bid; }
    else           { X = X2; P = P2p; lg = 6; nsp = 4; idx0 = bid - 128; }
    int ch = idx0 / nsp, split = idx0 % nsp;
    int n = 1 << lg;
    int total = n * n;
    int chunk = total / nsp;
    int b0 = split * chunk;
    const float* x = X + (size_t)ch * total + b0;
    float s = 0.f;
    for (int i = t; i < chunk; i += 256) {
      int idx = b0 + i;
      float v = x[i];
      s += (((idx >> lg) ^ idx) & 1) ? -v : v;
    }
#pragma unroll
    for (int off = 32; off > 0; off >>= 1) s += __shfl_down(s, off, 64);
    __shared__ float red[4];
    if ((t & 63) == 0) red[t >> 6] = s;
    __syncthreads();
    if (t == 0) P[ch * nsp + split] = red[0] + red[1] + red[2] + red[3];
    return;
  }
  // V pass: v[ch][nx][my] = sum_ny x[ch][nx][ny] * R[(my - s*ny) mod n1]
  int vbid = bid - 192;
  const float* X; float* V;
  int n1, n2, s, ch, nxg;
  if (vbid < 128)      { X = X1; V = V01; n1 = 256; n2 = 128; s = 2; ch = vbid >> 3; nxg = (vbid & 7) * 16; }
  else if (vbid < 192) { vbid -= 128; X = X2; V = V02; n1 = 256; n2 = 64; s = 4; ch = vbid >> 2; nxg = (vbid & 3) * 16; }
  else                 { vbid -= 192; X = X2; V = V12; n1 = 128; n2 = 64; s = 2; ch = vbid >> 2; nxg = (vbid & 3) * 16; }
  __shared__ float Rl[256];
  __shared__ float Xs[16 * 128];
  for (int i = t; i < n1; i += 256) Rl[i] = rtab_val(n1, n2, i);
  const float4* xch4 =
      (const float4*)(X + (size_t)ch * n2 * n2 + (size_t)nxg * n2);
  int nx4 = (16 * n2) >> 2;
  for (int i = t; i < nx4; i += 256) ((float4*)Xs)[i] = xch4[i];
  __syncthreads();
  int myq = t & 63;
  int nxq = t >> 6;
  int nmy = n1 >> 6;
  int mask = n1 - 1;
  float acc[4][4];
#pragma unroll
  for (int r = 0; r < 4; ++r)
#pragma unroll
    for (int c = 0; c < 4; ++c) acc[r][c] = 0.f;
  for (int ny = 0; ny < n2; ++ny) {
    float xv[4];
#pragma unroll
    for (int r = 0; r < 4; ++r) xv[r] = Xs[(4 * nxq + r) * n2 + ny];
#pragma unroll
    for (int c = 0; c < 4; ++c) {
      float rv = Rl[(myq + 64 * c - s * ny) & mask];
#pragma unroll
      for (int r = 0; r < 4; ++r) acc[r][c] += xv[r] * rv;
    }
  }
  float* vch = V + (size_t)ch * n2 * n1;
#pragma unroll
  for (int r = 0; r < 4; ++r)
    for (int c = 0; c < nmy; ++c)
      vch[(size_t)(nxg + 4 * nxq + r) * n1 + myq + 64 * c] = acc[r][c];
}

// k_main: u<640 fused U(LDS)+corr; u in [640,1088) self-corr.
// LDS: sRl(256) + ONE shared 4864-float region reused as: phase-A V staging,
// then Us rows, then epilogue buffer (never live simultaneously). 20 KB total.
__global__ __launch_bounds__(256) void k_main(const float* __restrict__ X0,
                                              const float* __restrict__ X1,
                                              const float* __restrict__ X2,
                                              const float* __restrict__ V01,
                                              const float* __restrict__ V02,
                                              const float* __restrict__ V12,
                                              const float* __restrict__ P1p,
                                              const float* __restrict__ P2p,
                                              float* __restrict__ out) {
  __shared__ float smem[5120];    // 20 KB
  float* sRl = smem;              // 256
  float* sh = smem + 256;         // 4864: staging / Us / epilogue (time-shared)
  int u = blockIdx.x;
  int t = threadIdx.x;
  int lane = t & 63;
  int wv = t >> 6;

  float accC[8][7];
#pragma unroll
  for (int i = 0; i < 8; ++i)
#pragma unroll
    for (int p = 0; p < 7; ++p) accC[i][p] = 0.f;

  int base, b, l2;

  if (u < 640) {
    // ================= fused U + corr =================
    const float* V; const float* Pp; const float* A1b;
    int n1, n2, s, ch, chunk, nsp, lgn1; float inv;
    if (u < 256)      { V = V01; Pp = P1p; nsp = 8; A1b = X0; n1 = 256; n2 = 128; s = 2; inv = 1.f / (128.f * 128.f); ch = u >> 4; chunk = u & 15; lgn1 = 8; base = 64; }
    else if (u < 512) { int w = u - 256; V = V02; Pp = P2p; nsp = 4; A1b = X0; n1 = 256; n2 = 64; s = 4; inv = 1.f / (64.f * 64.f); ch = w >> 4; chunk = w & 15; lgn1 = 8; base = 128; }
    else              { int w = u - 512; V = V12; Pp = P2p; nsp = 4; A1b = X1; n1 = 128; n2 = 64; s = 2; inv = 1.f / (64.f * 64.f); ch = w >> 3; chunk = w & 7; lgn1 = 7; base = 256; }
    int mask = n1 - 1;
    for (int i = t; i < n1; i += 256) sRl[i] = rtab_val(n1, n2, i);
    int mxg = chunk * 16;
    b = ch >> 3; l2 = ch & 7;
    const float* vch = V + (size_t)ch * n2 * n1;
    float Pv = 0.f;
    for (int i = 0; i < nsp; ++i) Pv += Pp[ch * nsp + i];
    float a = PI_F / (float)s;
    int per = 2 * s;
    // ---- phase A: U rows [mxg-2, mxg+17) -> sh[0..19*n1)
    if (n1 == 256) {
      int cid = t & 63;
      float4 acc[5];
#pragma unroll
      for (int j = 0; j < 5; ++j) acc[j] = make_float4(0.f, 0.f, 0.f, 0.f);
      for (int nx0 = 0; nx0 < n2; nx0 += 16) {
        __syncthreads();
        const float4* s4 = (const float4*)(vch + (size_t)nx0 * 256);
        for (int i = t; i < 1024; i += 256) ((float4*)sh)[i] = s4[i];
        __syncthreads();
#pragma unroll
        for (int k = 0; k < 16; ++k) {
          int nx = nx0 + k;
          float4 vv = *(const float4*)&sh[k * 256 + 4 * cid];
#pragma unroll
          for (int j = 0; j < 5; ++j) {
            int mx = (mxg - 2 + wv + 4 * j) & mask;
            float rv = sRl[(mx - s * nx) & mask];
            acc[j].x += rv * vv.x; acc[j].y += rv * vv.y;
            acc[j].z += rv * vv.z; acc[j].w += rv * vv.w;
          }
        }
      }
      __syncthreads();  // staging reads done before Us overwrites region
      float smy[4];
#pragma unroll
      for (int j = 0; j < 4; ++j) smy[j] = sinf(a * (float)((4 * cid + j) & (per - 1)));
#pragma unroll
      for (int j = 0; j < 5; ++j) {
        int rl = wv + 4 * j;
        if (rl < 19) {
          int mx = (mxg - 2 + rl) & mask;
          float q = inv * sinf(a * (float)(mx & (per - 1))) * Pv;
          float4 o = acc[j];
          o.x -= q * smy[0]; o.y -= q * smy[1]; o.z -= q * smy[2]; o.w -= q * smy[3];
          *(float4*)&sh[rl * 256 + 4 * cid] = o;
        }
      }
    } else {
      // n1 = 128 (p12)
      int cid = t & 31;
      int owner = t >> 5;  // 0..7
      float4 acc[3];
#pragma unroll
      for (int j = 0; j < 3; ++j) acc[j] = make_float4(0.f, 0.f, 0.f, 0.f);
      for (int nx0 = 0; nx0 < 64; nx0 += 16) {
        __syncthreads();
        const float4* s4 = (const float4*)(vch + (size_t)nx0 * 128);
        for (int i = t; i < 512; i += 256) ((float4*)sh)[i] = s4[i];
        __syncthreads();
#pragma unroll
        for (int k = 0; k < 16; ++k) {
          int nx = nx0 + k;
          float4 vv = *(const float4*)&sh[k * 128 + 4 * cid];
#pragma unroll
          for (int j = 0; j < 3; ++j) {
            int mx = (mxg - 2 + owner + 8 * j) & 127;
            float rv = sRl[(mx - 2 * nx) & 127];
            acc[j].x += rv * vv.x; acc[j].y += rv * vv.y;
            acc[j].z += rv * vv.z; acc[j].w += rv * vv.w;
          }
        }
      }
      __syncthreads();  // staging reads done before Us overwrites region
      float smy[4];
#pragma unroll
      for (int j = 0; j < 4; ++j) smy[j] = sinf(a * (float)((4 * cid + j) & 3));
#pragma unroll
      for (int j = 0; j < 3; ++j) {
        int rl = owner + 8 * j;
        if (rl < 19) {
          int mx = (mxg - 2 + rl) & 127;
          float q = inv * sinf(a * (float)(mx & 3)) * Pv;
          float4 o = acc[j];
          o.x -= q * smy[0]; o.y -= q * smy[1]; o.z -= q * smy[2]; o.w -= q * smy[3];
          *(float4*)&sh[rl * 128 + 4 * cid] = o;
        }
      }
    }
    __syncthreads();
    // ---- phase B: corr of A1 rows [mxg, mxg+16) against Us (LDS = sh)
    int lgtpr = lgn1 - 2;
    int tpr = 1 << lgtpr;
    int rif = 256 >> lgtpr;
    int rid = t >> lgtpr;
    int cid2 = t & (tpr - 1);
    int ty = cid2 * 4;
    int tym = (ty - 4) & mask;
    int n1sq = n1 * n1;
    const float* A1 = A1b + (size_t)(b * 8) * n1sq;
    for (int rr = 0; rr < 16; rr += rif) {
      int ri = rr + rid;  // 0..15
      const float* r0 = &sh[(ri + 2) * n1];
      const float* r1 = &sh[(ri + 1) * n1];
      const float* r2 = &sh[ri * n1];
      const float* r3 = &sh[(ri + 3) * n1];
      float4 a0 = *(const float4*)(r0 + tym);
      float4 b0 = *(const float4*)(r0 + ty);
      float4 a1 = *(const float4*)(r1 + tym);
      float4 b1 = *(const float4*)(r1 + ty);
      float4 b2 = *(const float4*)(r2 + ty);
      float4 a3 = *(const float4*)(r3 + tym);
      float4 b3 = *(const float4*)(r3 + ty);
      const float* rA = A1 + (size_t)(mxg + ri) * n1 + ty;
#pragma unroll
      for (int l1 = 0; l1 < 8; ++l1) {
        float4 xv = *(const float4*)(rA + (size_t)l1 * n1sq);
        accC[l1][0] += xv.x * b0.x + xv.y * b0.y + xv.z * b0.z + xv.w * b0.w;
        accC[l1][1] += xv.x * a0.w + xv.y * b0.x + xv.z * b0.y + xv.w * b0.z;
        accC[l1][2] += xv.x * a0.z + xv.y * a0.w + xv.z * b0.x + xv.w * b0.y;
        accC[l1][3] += xv.x * b1.x + xv.y * b1.y + xv.z * b1.z + xv.w * b1.w;
        accC[l1][4] += xv.x * a1.w + xv.y * b1.x + xv.z * b1.y + xv.w * b1.z;
        accC[l1][5] += xv.x * b2.x + xv.y * b2.y + xv.z * b2.z + xv.w * b2.w;
        accC[l1][6] += xv.x * a3.w + xv.y * b3.x + xv.z * b3.y + xv.w * b3.z;
      }
    }
  } else {
    // ================= self-corr (groups 0,3,5) =================
    int w = u - 640;
    const float* Ab; int loc, lgn1, lgc;
    if (w < 256)      { loc = w;       Ab = X0; lgn1 = 8; lgc = 4; base = 0;   }
    else if (w < 384) { loc = w - 256; Ab = X1; lgn1 = 7; lgc = 3; base = 192; }
    else              { loc = w - 384; Ab = X2; lgn1 = 6; lgc = 2; base = 320; }
    int n1 = 1 << lgn1;
    int mask = n1 - 1;
    int n1sq = n1 * n1;
    int chunk = loc & ((1 << lgc) - 1);
    int bl2 = loc >> lgc;
    b = bl2 >> 3; l2 = bl2 & 7;
    const float* A1 = Ab + (size_t)(b * 8) * n1sq;
    const float* A2 = Ab + (size_t)(b * 8 + l2) * n1sq;
    int lgtpr = lgn1 - 2;
    int tpr = 1 << lgtpr;
    int rif = 256 >> lgtpr;
    int rid = t >> lgtpr;
    int cid2 = t & (tpr - 1);
    int ty = cid2 * 4;
    int tym = (ty - 4) & mask;
    for (int rr = 0; rr < 16; rr += rif) {
      int row = chunk * 16 + rr + rid;
      const float* r0 = A2 + (size_t)row * n1;
      const float* r1 = A2 + (size_t)((row - 1) & mask) * n1;
      const float* r2 = A2 + (size_t)((row - 2) & mask) * n1;
      const float* r3 = A2 + (size_t)((row + 1) & mask) * n1;
      float4 a0 = *(const float4*)(r0 + tym);
      float4 b0 = *(const float4*)(r0 + ty);
      float4 a1 = *(const float4*)(r1 + tym);
      float4 b1 = *(const float4*)(r1 + ty);
      float4 b2 = *(const float4*)(r2 + ty);
      float4 a3 = *(const float4*)(r3 + tym);
      float4 b3 = *(const float4*)(r3 + ty);
      const float* rA = A1 + (size_t)row * n1 + ty;
#pragma unroll
      for (int l1 = 0; l1 < 8; ++l1) {
        float4 xv = *(const float4*)(rA + (size_t)l1 * n1sq);
        accC[l1][0] += xv.x * b0.x + xv.y * b0.y + xv.z * b0.z + xv.w * b0.w;
        accC[l1][1] += xv.x * a0.w + xv.y * b0.x + xv.z * b0.y + xv.w * b0.z;
        accC[l1][2] += xv.x * a0.z + xv.y * a0.w + xv.z * b0.x + xv.w * b0.y;
        accC[l1][3] += xv.x * b1.x + xv.y * b1.y + xv.z * b1.z + xv.w * b1.w;
        accC[l1][4] += xv.x * a1.w + xv.y * b1.x + xv.z * b1.y + xv.w * b1.z;
        accC[l1][5] += xv.x * b2.x + xv.y * b2.y + xv.z * b2.z + xv.w * b2.w;
        accC[l1][6] += xv.x * a3.w + xv.y * b3.x + xv.z * b3.y + xv.w * b3.z;
      }
    }
  }
  // ---- shared epilogue: 2-shfl fold + LDS transpose (stride 60) ----
  float* af = &accC[0][0];
#pragma unroll
  for (int j = 0; j < 56; ++j) {
    float v = af[j];
    v += __shfl_down(v, 32, 64);
    v += __shfl_down(v, 16, 64);
    af[j] = v;
  }
  __syncthreads();  // phase-B Us reads done before epilogue overwrites region
  if (lane < 16) {
    float* rowp = sh + (wv * 16 + lane) * 60;
#pragma unroll
    for (int j = 0; j < 14; ++j)
      *(float4*)&rowp[4 * j] =
          make_float4(af[4 * j], af[4 * j + 1], af[4 * j + 2], af[4 * j + 3]);
  }
  __syncthreads();
  if (t < 224) {
    int v = t >> 2, q = t & 3;
    float s2 = 0.f;
#pragma unroll
    for (int i = 0; i < 16; ++i) s2 += sh[(q * 16 + i) * 60 + v];
    s2 += __shfl_down(s2, 2, 64);
    s2 += __shfl_down(s2, 1, 64);
    if (q == 0) {
      int l1o = v / 7, p = v % 7;
      atomicAdd(&out[((size_t)b * 384 + base + l1o * 8 + l2) * 7 + p], s2);
    }
  }
}

extern "C" void kernel_launch(void* const* d_in, const int* in_sizes, int n_in,
                              void* d_out, int out_size, void* d_ws, size_t ws_size,
                              hipStream_t stream) {
  const float* X0 = (const float*)d_in[0];  // [2,8,256,256]
  const float* X1 = (const float*)d_in[1];  // [2,8,128,128]
  const float* X2 = (const float*)d_in[2];  // [2,8,64,64]
  float* out = (float*)d_out;               // [2,384,7]
  float* ws = (float*)d_ws;

  float* V01 = ws + 2359296;
  float* V02 = ws + 2883584;
  float* V12 = ws + 3145728;
  float* P1p = ws + 3276800;
  float* P2p = ws + 3276928;

  k_front<<<449, 256, 0, stream>>>(X1, X2, P1p, P2p, V01, V02, V12, out);
  k_main<<<1088, 256, 0, stream>>>(X0, X1, X2, V01, V02, V12, P1p, P2p, out);
}

// Round 14
// 106.946 us; speedup vs baseline: 1.0553x; 1.0553x over previous
//
#include <hip/hip_runtime.h>

#define PI_D 3.14159265358979323846
#define PI_F 3.14159265358979323846f

// ---- workspace layout (floats) ----
// V01 @ 2359296  : 524288    V02 @ 2883584 : 262144    V12 @ 3145728 : 131072
// P1p @ 3276800  : 128       P2p @ 3276928 : 64

__device__ inline float rtab_val(int n, int m2, int t) {
  if (t == 0) return 1.0f;
  double th = PI_D * (double)t / (double)n;
  double v = sin(th * (double)(m2 - 1)) / sin(th) + cos(th * (double)m2);
  return (float)(v / (double)m2);  // 1/m2 per axis
}

// Front kernel: bid 0..191 P partials; 192..447 V01 (col-split x2);
// 448..575 V02 (col-split x2); 576..639 V12; 640 zero d_out.
__global__ __launch_bounds__(256) void k_front(const float* __restrict__ X1,
                                               const float* __restrict__ X2,
                                               float* __restrict__ P1p,
                                               float* __restrict__ P2p,
                                               float* __restrict__ V01,
                                               float* __restrict__ V02,
                                               float* __restrict__ V12,
                                               float* __restrict__ out) {
  int bid = blockIdx.x;
  int t = threadIdx.x;
  if (bid == 640) {
    for (int i = t; i < 5376; i += 256) out[i] = 0.f;
    return;
  }
  if (bid < 192) {
    const float* X; float* P; int lg, nsp, idx0;
    if (bid < 128) { X = X1; P = P1p; lg = 7; nsp = 8; idx0 = bid; }
    else           { X = X2; P = P2p; lg = 6; nsp = 4; idx0 = bid - 128; }
    int ch = idx0 / nsp, split = idx0 % nsp;
    int n = 1 << lg;
    int total = n * n;
    int chunk = total / nsp;
    int b0 = split * chunk;
    const float* x = X + (size_t)ch * total + b0;
    float s = 0.f;
    for (int i = t; i < chunk; i += 256) {
      int idx = b0 + i;
      float v = x[i];
      s += (((idx >> lg) ^ idx) & 1) ? -v : v;
    }
#pragma unroll
    for (int off = 32; off > 0; off >>= 1) s += __shfl_down(s, off, 64);
    __shared__ float red[4];
    if ((t & 63) == 0) red[t >> 6] = s;
    __syncthreads();
    if (t == 0) P[ch * nsp + split] = red[0] + red[1] + red[2] + red[3];
    return;
  }
  // V pass: v[ch][nx][my] = sum_ny x[ch][nx][ny] * R[(my - s*ny) mod n1]
  int vbid = bid - 192;
  const float* X; float* V;
  int n1, n2, s, ch, nxg, colh, ncg;
  if (vbid < 256) {  // V01: 16ch x 8 nxg x 2 colhalf
    X = X1; V = V01; n1 = 256; n2 = 128; s = 2;
    ch = vbid >> 4; nxg = ((vbid >> 1) & 7) * 16; colh = vbid & 1; ncg = 2;
  } else if (vbid < 384) {  // V02: 16ch x 4 nxg x 2 colhalf
    int w = vbid - 256;
    X = X2; V = V02; n1 = 256; n2 = 64; s = 4;
    ch = w >> 3; nxg = ((w >> 1) & 3) * 16; colh = w & 1; ncg = 2;
  } else {  // V12: 16ch x 4 nxg
    int w = vbid - 384;
    X = X2; V = V12; n1 = 128; n2 = 64; s = 2;
    ch = w >> 2; nxg = (w & 3) * 16; colh = 0; ncg = 2;
  }
  __shared__ float Rl[256];
  __shared__ float Xs[16 * 128];
  for (int i = t; i < n1; i += 256) Rl[i] = rtab_val(n1, n2, i);
  const float4* xch4 =
      (const float4*)(X + (size_t)ch * n2 * n2 + (size_t)nxg * n2);
  int nx4 = (16 * n2) >> 2;
  for (int i = t; i < nx4; i += 256) ((float4*)Xs)[i] = xch4[i];
  __syncthreads();
  int myq = (t & 63) + colh * 128;
  int nxq = t >> 6;
  int mask = n1 - 1;
  float acc[4][2];
#pragma unroll
  for (int r = 0; r < 4; ++r)
#pragma unroll
    for (int c = 0; c < 2; ++c) acc[r][c] = 0.f;
  for (int ny = 0; ny < n2; ++ny) {
    float xv[4];
#pragma unroll
    for (int r = 0; r < 4; ++r) xv[r] = Xs[(4 * nxq + r) * n2 + ny];
#pragma unroll
    for (int c = 0; c < 2; ++c) {
      float rv = Rl[(myq + 64 * c - s * ny) & mask];
#pragma unroll
      for (int r = 0; r < 4; ++r) acc[r][c] += xv[r] * rv;
    }
  }
  float* vch = V + (size_t)ch * n2 * n1;
#pragma unroll
  for (int r = 0; r < 4; ++r)
    for (int c = 0; c < 2; ++c)
      vch[(size_t)(nxg + 4 * nxq + r) * n1 + myq + 64 * c] = acc[r][c];
}

// k_main: u<640 fused U(LDS)+corr; u in [640,1088) self-corr.
// LDS: sRl(256) + one 8192-float region time-shared: 32-row V staging ->
// Us rows -> epilogue. 33 KB.
__global__ __launch_bounds__(256) void k_main(const float* __restrict__ X0,
                                              const float* __restrict__ X1,
                                              const float* __restrict__ X2,
                                              const float* __restrict__ V01,
                                              const float* __restrict__ V02,
                                              const float* __restrict__ V12,
                                              const float* __restrict__ P1p,
                                              const float* __restrict__ P2p,
                                              float* __restrict__ out) {
  __shared__ float smem[8448];    // 33 KB
  float* sRl = smem;              // 256
  float* sh = smem + 256;         // 8192: staging / Us / epilogue (time-shared)
  int u = blockIdx.x;
  int t = threadIdx.x;
  int lane = t & 63;
  int wv = t >> 6;

  float accC[8][7];
#pragma unroll
  for (int i = 0; i < 8; ++i)
#pragma unroll
    for (int p = 0; p < 7; ++p) accC[i][p] = 0.f;

  int base, b, l2;

  if (u < 640) {
    // ================= fused U + corr =================
    const float* V; const float* Pp; const float* A1b;
    int n1, n2, s, ch, chunk, nsp, lgn1; float inv;
    if (u < 256)      { V = V01; Pp = P1p; nsp = 8; A1b = X0; n1 = 256; n2 = 128; s = 2; inv = 1.f / (128.f * 128.f); ch = u >> 4; chunk = u & 15; lgn1 = 8; base = 64; }
    else if (u < 512) { int w = u - 256; V = V02; Pp = P2p; nsp = 4; A1b = X0; n1 = 256; n2 = 64; s = 4; inv = 1.f / (64.f * 64.f); ch = w >> 4; chunk = w & 15; lgn1 = 8; base = 128; }
    else              { int w = u - 512; V = V12; Pp = P2p; nsp = 4; A1b = X1; n1 = 128; n2 = 64; s = 2; inv = 1.f / (64.f * 64.f); ch = w >> 3; chunk = w & 7; lgn1 = 7; base = 256; }
    int mask = n1 - 1;
    for (int i = t; i < n1; i += 256) sRl[i] = rtab_val(n1, n2, i);
    int mxg = chunk * 16;
    b = ch >> 3; l2 = ch & 7;
    const float* vch = V + (size_t)ch * n2 * n1;
    float Pv = 0.f;
    for (int i = 0; i < nsp; ++i) Pv += Pp[ch * nsp + i];
    float a = PI_F / (float)s;
    int per = 2 * s;
    // ---- phase A: U rows [mxg-2, mxg+17) -> sh[0..19*n1)
    if (n1 == 256) {
      int cid = t & 63;
      float4 acc[5];
#pragma unroll
      for (int j = 0; j < 5; ++j) acc[j] = make_float4(0.f, 0.f, 0.f, 0.f);
      for (int nx0 = 0; nx0 < n2; nx0 += 32) {   // 32-row staging chunks
        __syncthreads();
        const float4* s4 = (const float4*)(vch + (size_t)nx0 * 256);
        for (int i = t; i < 2048; i += 256) ((float4*)sh)[i] = s4[i];
        __syncthreads();
#pragma unroll 8
        for (int k = 0; k < 32; ++k) {
          int nx = nx0 + k;
          float4 vv = *(const float4*)&sh[k * 256 + 4 * cid];
#pragma unroll
          for (int j = 0; j < 5; ++j) {
            int mx = (mxg - 2 + wv + 4 * j) & mask;
            float rv = sRl[(mx - s * nx) & mask];
            acc[j].x += rv * vv.x; acc[j].y += rv * vv.y;
            acc[j].z += rv * vv.z; acc[j].w += rv * vv.w;
          }
        }
      }
      __syncthreads();  // staging reads done before Us overwrites region
      float smy[4];
#pragma unroll
      for (int j = 0; j < 4; ++j) smy[j] = sinf(a * (float)((4 * cid + j) & (per - 1)));
#pragma unroll
      for (int j = 0; j < 5; ++j) {
        int rl = wv + 4 * j;
        if (rl < 19) {
          int mx = (mxg - 2 + rl) & mask;
          float q = inv * sinf(a * (float)(mx & (per - 1))) * Pv;
          float4 o = acc[j];
          o.x -= q * smy[0]; o.y -= q * smy[1]; o.z -= q * smy[2]; o.w -= q * smy[3];
          *(float4*)&sh[rl * 256 + 4 * cid] = o;
        }
      }
    } else {
      // n1 = 128 (p12): stage the whole 64x128 V channel once
      int cid = t & 31;
      int owner = t >> 5;  // 0..7
      float4 acc[3];
#pragma unroll
      for (int j = 0; j < 3; ++j) acc[j] = make_float4(0.f, 0.f, 0.f, 0.f);
      __syncthreads();
      {
        const float4* s4 = (const float4*)vch;
        for (int i = t; i < 2048; i += 256) ((float4*)sh)[i] = s4[i];
      }
      __syncthreads();
#pragma unroll 8
      for (int nx = 0; nx < 64; ++nx) {
        float4 vv = *(const float4*)&sh[nx * 128 + 4 * cid];
#pragma unroll
        for (int j = 0; j < 3; ++j) {
          int mx = (mxg - 2 + owner + 8 * j) & 127;
          float rv = sRl[(mx - 2 * nx) & 127];
          acc[j].x += rv * vv.x; acc[j].y += rv * vv.y;
          acc[j].z += rv * vv.z; acc[j].w += rv * vv.w;
        }
      }
      __syncthreads();  // staging reads done before Us overwrites region
      float smy[4];
#pragma unroll
      for (int j = 0; j < 4; ++j) smy[j] = sinf(a * (float)((4 * cid + j) & 3));
#pragma unroll
      for (int j = 0; j < 3; ++j) {
        int rl = owner + 8 * j;
        if (rl < 19) {
          int mx = (mxg - 2 + rl) & 127;
          float q = inv * sinf(a * (float)(mx & 3)) * Pv;
          float4 o = acc[j];
          o.x -= q * smy[0]; o.y -= q * smy[1]; o.z -= q * smy[2]; o.w -= q * smy[3];
          *(float4*)&sh[rl * 128 + 4 * cid] = o;
        }
      }
    }
    __syncthreads();
    // ---- phase B: corr of A1 rows [mxg, mxg+16) against Us (LDS = sh)
    int lgtpr = lgn1 - 2;
    int tpr = 1 << lgtpr;
    int rif = 256 >> lgtpr;
    int rid = t >> lgtpr;
    int cid2 = t & (tpr - 1);
    int ty = cid2 * 4;
    int tym = (ty - 4) & mask;
    int n1sq = n1 * n1;
    const float* A1 = A1b + (size_t)(b * 8) * n1sq;
    for (int rr = 0; rr < 16; rr += rif) {
      int ri = rr + rid;  // 0..15
      const float* r0 = &sh[(ri + 2) * n1];
      const float* r1 = &sh[(ri + 1) * n1];
      const float* r2 = &sh[ri * n1];
      const float* r3 = &sh[(ri + 3) * n1];
      float4 a0 = *(const float4*)(r0 + tym);
      float4 b0 = *(const float4*)(r0 + ty);
      float4 a1 = *(const float4*)(r1 + tym);
      float4 b1 = *(const float4*)(r1 + ty);
      float4 b2 = *(const float4*)(r2 + ty);
      float4 a3 = *(const float4*)(r3 + tym);
      float4 b3 = *(const float4*)(r3 + ty);
      const float* rA = A1 + (size_t)(mxg + ri) * n1 + ty;
#pragma unroll
      for (int l1 = 0; l1 < 8; ++l1) {
        float4 xv = *(const float4*)(rA + (size_t)l1 * n1sq);
        accC[l1][0] += xv.x * b0.x + xv.y * b0.y + xv.z * b0.z + xv.w * b0.w;
        accC[l1][1] += xv.x * a0.w + xv.y * b0.x + xv.z * b0.y + xv.w * b0.z;
        accC[l1][2] += xv.x * a0.z + xv.y * a0.w + xv.z * b0.x + xv.w * b0.y;
        accC[l1][3] += xv.x * b1.x + xv.y * b1.y + xv.z * b1.z + xv.w * b1.w;
        accC[l1][4] += xv.x * a1.w + xv.y * b1.x + xv.z * b1.y + xv.w * b1.z;
        accC[l1][5] += xv.x * b2.x + xv.y * b2.y + xv.z * b2.z + xv.w * b2.w;
        accC[l1][6] += xv.x * a3.w + xv.y * b3.x + xv.z * b3.y + xv.w * b3.z;
      }
    }
  } else {
    // ================= self-corr (groups 0,3,5) =================
    int w = u - 640;
    const float* Ab; int loc, lgn1, lgc;
    if (w < 256)      { loc = w;       Ab = X0; lgn1 = 8; lgc = 4; base = 0;   }
    else if (w < 384) { loc = w - 256; Ab = X1; lgn1 = 7; lgc = 3; base = 192; }
    else              { loc = w - 384; Ab = X2; lgn1 = 6; lgc = 2; base = 320; }
    int n1 = 1 << lgn1;
    int mask = n1 - 1;
    int n1sq = n1 * n1;
    int chunk = loc & ((1 << lgc) - 1);
    int bl2 = loc >> lgc;
    b = bl2 >> 3; l2 = bl2 & 7;
    const float* A1 = Ab + (size_t)(b * 8) * n1sq;
    const float* A2 = Ab + (size_t)(b * 8 + l2) * n1sq;
    int lgtpr = lgn1 - 2;
    int tpr = 1 << lgtpr;
    int rif = 256 >> lgtpr;
    int rid = t >> lgtpr;
    int cid2 = t & (tpr - 1);
    int ty = cid2 * 4;
    int tym = (ty - 4) & mask;
    for (int rr = 0; rr < 16; rr += rif) {
      int row = chunk * 16 + rr + rid;
      const float* r0 = A2 + (size_t)row * n1;
      const float* r1 = A2 + (size_t)((row - 1) & mask) * n1;
      const float* r2 = A2 + (size_t)((row - 2) & mask) * n1;
      const float* r3 = A2 + (size_t)((row + 1) & mask) * n1;
      float4 a0 = *(const float4*)(r0 + tym);
      float4 b0 = *(const float4*)(r0 + ty);
      float4 a1 = *(const float4*)(r1 + tym);
      float4 b1 = *(const float4*)(r1 + ty);
      float4 b2 = *(const float4*)(r2 + ty);
      float4 a3 = *(const float4*)(r3 + tym);
      float4 b3 = *(const float4*)(r3 + ty);
      const float* rA = A1 + (size_t)row * n1 + ty;
#pragma unroll
      for (int l1 = 0; l1 < 8; ++l1) {
        float4 xv = *(const float4*)(rA + (size_t)l1 * n1sq);
        accC[l1][0] += xv.x * b0.x + xv.y * b0.y + xv.z * b0.z + xv.w * b0.w;
        accC[l1][1] += xv.x * a0.w + xv.y * b0.x + xv.z * b0.y + xv.w * b0.z;
        accC[l1][2] += xv.x * a0.z + xv.y * a0.w + xv.z * b0.x + xv.w * b0.y;
        accC[l1][3] += xv.x * b1.x + xv.y * b1.y + xv.z * b1.z + xv.w * b1.w;
        accC[l1][4] += xv.x * a1.w + xv.y * b1.x + xv.z * b1.y + xv.w * b1.z;
        accC[l1][5] += xv.x * b2.x + xv.y * b2.y + xv.z * b2.z + xv.w * b2.w;
        accC[l1][6] += xv.x * a3.w + xv.y * b3.x + xv.z * b3.y + xv.w * b3.z;
      }
    }
  }
  // ---- shared epilogue: 2-shfl fold + LDS transpose (stride 60) ----
  float* af = &accC[0][0];
#pragma unroll
  for (int j = 0; j < 56; ++j) {
    float v = af[j];
    v += __shfl_down(v, 32, 64);
    v += __shfl_down(v, 16, 64);
    af[j] = v;
  }
  __syncthreads();  // phase-B Us reads done before epilogue overwrites region
  if (lane < 16) {
    float* rowp = sh + (wv * 16 + lane) * 60;
#pragma unroll
    for (int j = 0; j < 14; ++j)
      *(float4*)&rowp[4 * j] =
          make_float4(af[4 * j], af[4 * j + 1], af[4 * j + 2], af[4 * j + 3]);
  }
  __syncthreads();
  if (t < 224) {
    int v = t >> 2, q = t & 3;
    float s2 = 0.f;
#pragma unroll
    for (int i = 0; i < 16; ++i) s2 += sh[(q * 16 + i) * 60 + v];
    s2 += __shfl_down(s2, 2, 64);
    s2 += __shfl_down(s2, 1, 64);
    if (q == 0) {
      int l1o = v / 7, p = v % 7;
      atomicAdd(&out[((size_t)b * 384 + base + l1o * 8 + l2) * 7 + p], s2);
    }
  }
}

extern "C" void kernel_launch(void* const* d_in, const int* in_sizes, int n_in,
                              void* d_out, int out_size, void* d_ws, size_t ws_size,
                              hipStream_t stream) {
  const float* X0 = (const float*)d_in[0];  // [2,8,256,256]
  const float* X1 = (const float*)d_in[1];  // [2,8,128,128]
  const float* X2 = (const float*)d_in[2];  // [2,8,64,64]
  float* out = (float*)d_out;               // [2,384,7]
  float* ws = (float*)d_ws;

  float* V01 = ws + 2359296;
  float* V02 = ws + 2883584;
  float* V12 = ws + 3145728;
  float* P1p = ws + 3276800;
  float* P2p = ws + 3276928;

  k_front<<<641, 256, 0, stream>>>(X1, X2, P1p, P2p, V01, V02, V12, out);
  k_main<<<1088, 256, 0, stream>>>(X0, X1, X2, V01, V02, V12, P1p, P2p, out);
}

// Round 15
// 103.521 us; speedup vs baseline: 1.0902x; 1.0331x over previous
//
#include <hip/hip_runtime.h>

#define PI_D 3.14159265358979323846
#define PI_F 3.14159265358979323846f

// ---- workspace layout (floats) ----
// V01 @ 2359296  : 524288    V02 @ 2883584 : 262144    V12 @ 3145728 : 131072
// P1p @ 3276800  : 128       P2p @ 3276928 : 64

__device__ inline float rtab_val(int n, int m2, int t) {
  if (t == 0) return 1.0f;
  double th = PI_D * (double)t / (double)n;
  double v = sin(th * (double)(m2 - 1)) / sin(th) + cos(th * (double)m2);
  return (float)(v / (double)m2);  // 1/m2 per axis
}

// Front kernel: bid 0..191 P partials; 192..447 V01 (col-split x2);
// 448..575 V02 (col-split x2); 576..639 V12; 640 zero d_out. (proven R14)
__global__ __launch_bounds__(256) void k_front(const float* __restrict__ X1,
                                               const float* __restrict__ X2,
                                               float* __restrict__ P1p,
                                               float* __restrict__ P2p,
                                               float* __restrict__ V01,
                                               float* __restrict__ V02,
                                               float* __restrict__ V12,
                                               float* __restrict__ out) {
  int bid = blockIdx.x;
  int t = threadIdx.x;
  if (bid == 640) {
    for (int i = t; i < 5376; i += 256) out[i] = 0.f;
    return;
  }
  if (bid < 192) {
    const float* X; float* P; int lg, nsp, idx0;
    if (bid < 128) { X = X1; P = P1p; lg = 7; nsp = 8; idx0 = bid; }
    else           { X = X2; P = P2p; lg = 6; nsp = 4; idx0 = bid - 128; }
    int ch = idx0 / nsp, split = idx0 % nsp;
    int n = 1 << lg;
    int total = n * n;
    int chunk = total / nsp;
    int b0 = split * chunk;
    const float* x = X + (size_t)ch * total + b0;
    float s = 0.f;
    for (int i = t; i < chunk; i += 256) {
      int idx = b0 + i;
      float v = x[i];
      s += (((idx >> lg) ^ idx) & 1) ? -v : v;
    }
#pragma unroll
    for (int off = 32; off > 0; off >>= 1) s += __shfl_down(s, off, 64);
    __shared__ float red[4];
    if ((t & 63) == 0) red[t >> 6] = s;
    __syncthreads();
    if (t == 0) P[ch * nsp + split] = red[0] + red[1] + red[2] + red[3];
    return;
  }
  int vbid = bid - 192;
  const float* X; float* V;
  int n1, n2, s, ch, nxg, colh;
  if (vbid < 256) {
    X = X1; V = V01; n1 = 256; n2 = 128; s = 2;
    ch = vbid >> 4; nxg = ((vbid >> 1) & 7) * 16; colh = vbid & 1;
  } else if (vbid < 384) {
    int w = vbid - 256;
    X = X2; V = V02; n1 = 256; n2 = 64; s = 4;
    ch = w >> 3; nxg = ((w >> 1) & 3) * 16; colh = w & 1;
  } else {
    int w = vbid - 384;
    X = X2; V = V12; n1 = 128; n2 = 64; s = 2;
    ch = w >> 2; nxg = (w & 3) * 16; colh = 0;
  }
  __shared__ float Rl[256];
  __shared__ float Xs[16 * 128];
  for (int i = t; i < n1; i += 256) Rl[i] = rtab_val(n1, n2, i);
  const float4* xch4 =
      (const float4*)(X + (size_t)ch * n2 * n2 + (size_t)nxg * n2);
  int nx4 = (16 * n2) >> 2;
  for (int i = t; i < nx4; i += 256) ((float4*)Xs)[i] = xch4[i];
  __syncthreads();
  int myq = (t & 63) + colh * 128;
  int nxq = t >> 6;
  int mask = n1 - 1;
  float acc[4][2];
#pragma unroll
  for (int r = 0; r < 4; ++r)
#pragma unroll
    for (int c = 0; c < 2; ++c) acc[r][c] = 0.f;
  for (int ny = 0; ny < n2; ++ny) {
    float xv[4];
#pragma unroll
    for (int r = 0; r < 4; ++r) xv[r] = Xs[(4 * nxq + r) * n2 + ny];
#pragma unroll
    for (int c = 0; c < 2; ++c) {
      float rv = Rl[(myq + 64 * c - s * ny) & mask];
#pragma unroll
      for (int r = 0; r < 4; ++r) acc[r][c] += xv[r] * rv;
    }
  }
  float* vch = V + (size_t)ch * n2 * n1;
#pragma unroll
  for (int r = 0; r < 4; ++r)
    for (int c = 0; c < 2; ++c)
      vch[(size_t)(nxg + 4 * nxq + r) * n1 + myq + 64 * c] = acc[r][c];
}

// k_main: u<640 fused U+corr (V read direct from global; R4 float4 table);
// u in [640,1088) self-corr. LDS: sRl 256 + R4 1024 + sh 4864 = 24 KB.
__global__ __launch_bounds__(256) void k_main(const float* __restrict__ X0,
                                              const float* __restrict__ X1,
                                              const float* __restrict__ X2,
                                              const float* __restrict__ V01,
                                              const float* __restrict__ V02,
                                              const float* __restrict__ V12,
                                              const float* __restrict__ P1p,
                                              const float* __restrict__ P2p,
                                              float* __restrict__ out) {
  __shared__ float sRl[256];
  __shared__ float4 R4[256];
  __shared__ float sh[4864];  // Us 19*256 / epilogue (time-shared)
  int u = blockIdx.x;
  int t = threadIdx.x;
  int lane = t & 63;
  int wv = t >> 6;

  float accC[8][7];
#pragma unroll
  for (int i = 0; i < 8; ++i)
#pragma unroll
    for (int p = 0; p < 7; ++p) accC[i][p] = 0.f;

  int base, b, l2;

  if (u < 640) {
    // ================= fused U + corr =================
    const float* V; const float* Pp; const float* A1b;
    int n1, n2, s, ch, chunk, nsp, lgn1; float inv;
    if (u < 256)      { V = V01; Pp = P1p; nsp = 8; A1b = X0; n1 = 256; n2 = 128; s = 2; inv = 1.f / (128.f * 128.f); ch = u >> 4; chunk = u & 15; lgn1 = 8; base = 64; }
    else if (u < 512) { int w = u - 256; V = V02; Pp = P2p; nsp = 4; A1b = X0; n1 = 256; n2 = 64; s = 4; inv = 1.f / (64.f * 64.f); ch = w >> 4; chunk = w & 15; lgn1 = 8; base = 128; }
    else              { int w = u - 512; V = V12; Pp = P2p; nsp = 4; A1b = X1; n1 = 128; n2 = 64; s = 2; inv = 1.f / (64.f * 64.f); ch = w >> 3; chunk = w & 7; lgn1 = 7; base = 256; }
    int mask = n1 - 1;
    for (int i = t; i < n1; i += 256) sRl[i] = rtab_val(n1, n2, i);
    __syncthreads();
    for (int i = t; i < n1; i += 256)
      R4[i] = make_float4(sRl[i], sRl[(i + 1) & mask], sRl[(i + 2) & mask],
                          sRl[(i + 3) & mask]);
    __syncthreads();
    int mxg = chunk * 16;
    b = ch >> 3; l2 = ch & 7;
    const float* vch = V + (size_t)ch * n2 * n1;
    float Pv = 0.f;
    for (int i = 0; i < nsp; ++i) Pv += Pp[ch * nsp + i];
    float a = PI_F / (float)s;
    int per = 2 * s;
    // ---- phase A: U rows [mxg-2, mxg+17) -> sh[0..19*n1), V from global
    if (n1 == 256) {
      int cid = t & 63;
      int rb = mxg - 2 + 5 * wv;  // wave owns rows rb..rb+4 (rl = 5wv+j)
      float4 acc[5];
#pragma unroll
      for (int j = 0; j < 5; ++j) acc[j] = make_float4(0.f, 0.f, 0.f, 0.f);
      float4 vv = *(const float4*)(vch + 4 * cid);
      for (int nx = 0; nx < n2; ++nx) {
        float4 vvn;
        if (nx + 1 < n2) vvn = *(const float4*)(vch + (size_t)(nx + 1) * 256 + 4 * cid);
        int ib = (rb - s * nx) & mask;
        float4 r03 = R4[ib];
        float r4v = sRl[(ib + 4) & mask];
        float rv[5] = {r03.x, r03.y, r03.z, r03.w, r4v};
#pragma unroll
        for (int j = 0; j < 5; ++j) {
          acc[j].x += rv[j] * vv.x; acc[j].y += rv[j] * vv.y;
          acc[j].z += rv[j] * vv.z; acc[j].w += rv[j] * vv.w;
        }
        vv = vvn;
      }
      float smy[4];
#pragma unroll
      for (int j = 0; j < 4; ++j) smy[j] = sinf(a * (float)((4 * cid + j) & (per - 1)));
#pragma unroll
      for (int j = 0; j < 5; ++j) {
        int rl = 5 * wv + j;
        if (rl < 19) {
          int mx = (mxg - 2 + rl) & mask;
          float q = inv * sinf(a * (float)(mx & (per - 1))) * Pv;
          float4 o = acc[j];
          o.x -= q * smy[0]; o.y -= q * smy[1]; o.z -= q * smy[2]; o.w -= q * smy[3];
          *(float4*)&sh[rl * 256 + 4 * cid] = o;
        }
      }
    } else {
      // n1 = 128 (p12): 8 owners x 3 consecutive rows
      int cid = t & 31;
      int owner = t >> 5;  // 0..7
      int rb = mxg - 2 + 3 * owner;  // rows rl = 3*owner+j, j=0..2
      float4 acc[3];
#pragma unroll
      for (int j = 0; j < 3; ++j) acc[j] = make_float4(0.f, 0.f, 0.f, 0.f);
      float4 vv = *(const float4*)(vch + 4 * cid);
      for (int nx = 0; nx < 64; ++nx) {
        float4 vvn;
        if (nx + 1 < 64) vvn = *(const float4*)(vch + (size_t)(nx + 1) * 128 + 4 * cid);
        int ib = (rb - 2 * nx) & 127;
        float4 r03 = R4[ib];
        float rv[3] = {r03.x, r03.y, r03.z};
#pragma unroll
        for (int j = 0; j < 3; ++j) {
          acc[j].x += rv[j] * vv.x; acc[j].y += rv[j] * vv.y;
          acc[j].z += rv[j] * vv.z; acc[j].w += rv[j] * vv.w;
        }
        vv = vvn;
      }
      float smy[4];
#pragma unroll
      for (int j = 0; j < 4; ++j) smy[j] = sinf(a * (float)((4 * cid + j) & 3));
#pragma unroll
      for (int j = 0; j < 3; ++j) {
        int rl = 3 * owner + j;
        if (rl < 19) {
          int mx = (mxg - 2 + rl) & 127;
          float q = inv * sinf(a * (float)(mx & 3)) * Pv;
          float4 o = acc[j];
          o.x -= q * smy[0]; o.y -= q * smy[1]; o.z -= q * smy[2]; o.w -= q * smy[3];
          *(float4*)&sh[rl * 128 + 4 * cid] = o;
        }
      }
    }
    __syncthreads();
    // ---- phase B: corr of A1 rows [mxg, mxg+16) against Us (LDS = sh)
    int lgtpr = lgn1 - 2;
    int tpr = 1 << lgtpr;
    int rif = 256 >> lgtpr;
    int rid = t >> lgtpr;
    int cid2 = t & (tpr - 1);
    int ty = cid2 * 4;
    int tym = (ty - 4) & mask;
    int n1sq = n1 * n1;
    const float* A1 = A1b + (size_t)(b * 8) * n1sq;
    for (int rr = 0; rr < 16; rr += rif) {
      int ri = rr + rid;  // 0..15
      const float* r0 = &sh[(ri + 2) * n1];
      const float* r1 = &sh[(ri + 1) * n1];
      const float* r2 = &sh[ri * n1];
      const float* r3 = &sh[(ri + 3) * n1];
      float4 a0 = *(const float4*)(r0 + tym);
      float4 b0 = *(const float4*)(r0 + ty);
      float4 a1 = *(const float4*)(r1 + tym);
      float4 b1 = *(const float4*)(r1 + ty);
      float4 b2 = *(const float4*)(r2 + ty);
      float4 a3 = *(const float4*)(r3 + tym);
      float4 b3 = *(const float4*)(r3 + ty);
      const float* rA = A1 + (size_t)(mxg + ri) * n1 + ty;
#pragma unroll
      for (int l1 = 0; l1 < 8; ++l1) {
        float4 xv = *(const float4*)(rA + (size_t)l1 * n1sq);
        accC[l1][0] += xv.x * b0.x + xv.y * b0.y + xv.z * b0.z + xv.w * b0.w;
        accC[l1][1] += xv.x * a0.w + xv.y * b0.x + xv.z * b0.y + xv.w * b0.z;
        accC[l1][2] += xv.x * a0.z + xv.y * a0.w + xv.z * b0.x + xv.w * b0.y;
        accC[l1][3] += xv.x * b1.x + xv.y * b1.y + xv.z * b1.z + xv.w * b1.w;
        accC[l1][4] += xv.x * a1.w + xv.y * b1.x + xv.z * b1.y + xv.w * b1.z;
        accC[l1][5] += xv.x * b2.x + xv.y * b2.y + xv.z * b2.z + xv.w * b2.w;
        accC[l1][6] += xv.x * a3.w + xv.y * b3.x + xv.z * b3.y + xv.w * b3.z;
      }
    }
  } else {
    // ================= self-corr (groups 0,3,5) =================
    int w = u - 640;
    const float* Ab; int loc, lgn1, lgc;
    if (w < 256)      { loc = w;       Ab = X0; lgn1 = 8; lgc = 4; base = 0;   }
    else if (w < 384) { loc = w - 256; Ab = X1; lgn1 = 7; lgc = 3; base = 192; }
    else              { loc = w - 384; Ab = X2; lgn1 = 6; lgc = 2; base = 320; }
    int n1 = 1 << lgn1;
    int mask = n1 - 1;
    int n1sq = n1 * n1;
    int chunk = loc & ((1 << lgc) - 1);
    int bl2 = loc >> lgc;
    b = bl2 >> 3; l2 = bl2 & 7;
    const float* A1 = Ab + (size_t)(b * 8) * n1sq;
    const float* A2 = Ab + (size_t)(b * 8 + l2) * n1sq;
    int lgtpr = lgn1 - 2;
    int tpr = 1 << lgtpr;
    int rif = 256 >> lgtpr;
    int rid = t >> lgtpr;
    int cid2 = t & (tpr - 1);
    int ty = cid2 * 4;
    int tym = (ty - 4) & mask;
    for (int rr = 0; rr < 16; rr += rif) {
      int row = chunk * 16 + rr + rid;
      const float* r0 = A2 + (size_t)row * n1;
      const float* r1 = A2 + (size_t)((row - 1) & mask) * n1;
      const float* r2 = A2 + (size_t)((row - 2) & mask) * n1;
      const float* r3 = A2 + (size_t)((row + 1) & mask) * n1;
      float4 a0 = *(const float4*)(r0 + tym);
      float4 b0 = *(const float4*)(r0 + ty);
      float4 a1 = *(const float4*)(r1 + tym);
      float4 b1 = *(const float4*)(r1 + ty);
      float4 b2 = *(const float4*)(r2 + ty);
      float4 a3 = *(const float4*)(r3 + tym);
      float4 b3 = *(const float4*)(r3 + ty);
      const float* rA = A1 + (size_t)row * n1 + ty;
#pragma unroll
      for (int l1 = 0; l1 < 8; ++l1) {
        float4 xv = *(const float4*)(rA + (size_t)l1 * n1sq);
        accC[l1][0] += xv.x * b0.x + xv.y * b0.y + xv.z * b0.z + xv.w * b0.w;
        accC[l1][1] += xv.x * a0.w + xv.y * b0.x + xv.z * b0.y + xv.w * b0.z;
        accC[l1][2] += xv.x * a0.z + xv.y * a0.w + xv.z * b0.x + xv.w * b0.y;
        accC[l1][3] += xv.x * b1.x + xv.y * b1.y + xv.z * b1.z + xv.w * b1.w;
        accC[l1][4] += xv.x * a1.w + xv.y * b1.x + xv.z * b1.y + xv.w * b1.z;
        accC[l1][5] += xv.x * b2.x + xv.y * b2.y + xv.z * b2.z + xv.w * b2.w;
        accC[l1][6] += xv.x * a3.w + xv.y * b3.x + xv.z * b3.y + xv.w * b3.z;
      }
    }
  }
  // ---- shared epilogue: 2-shfl fold + LDS transpose (stride 60) ----
  float* af = &accC[0][0];
#pragma unroll
  for (int j = 0; j < 56; ++j) {
    float v = af[j];
    v += __shfl_down(v, 32, 64);
    v += __shfl_down(v, 16, 64);
    af[j] = v;
  }
  __syncthreads();  // phase-B Us reads done before epilogue overwrites region
  if (lane < 16) {
    float* rowp = sh + (wv * 16 + lane) * 60;
#pragma unroll
    for (int j = 0; j < 14; ++j)
      *(float4*)&rowp[4 * j] =
          make_float4(af[4 * j], af[4 * j + 1], af[4 * j + 2], af[4 * j + 3]);
  }
  __syncthreads();
  if (t < 224) {
    int v = t >> 2, q = t & 3;
    float s2 = 0.f;
#pragma unroll
    for (int i = 0; i < 16; ++i) s2 += sh[(q * 16 + i) * 60 + v];
    s2 += __shfl_down(s2, 2, 64);
    s2 += __shfl_down(s2, 1, 64);
    if (q == 0) {
      int l1o = v / 7, p = v % 7;
      atomicAdd(&out[((size_t)b * 384 + base + l1o * 8 + l2) * 7 + p], s2);
    }
  }
}

extern "C" void kernel_launch(void* const* d_in, const int* in_sizes, int n_in,
                              void* d_out, int out_size, void* d_ws, size_t ws_size,
                              hipStream_t stream) {
  const float* X0 = (const float*)d_in[0];  // [2,8,256,256]
  const float* X1 = (const float*)d_in[1];  // [2,8,128,128]
  const float* X2 = (const float*)d_in[2];  // [2,8,64,64]
  float* out = (float*)d_out;               // [2,384,7]
  float* ws = (float*)d_ws;

  float* V01 = ws + 2359296;
  float* V02 = ws + 2883584;
  float* V12 = ws + 3145728;
  float* P1p = ws + 3276800;
  float* P2p = ws + 3276928;

  k_front<<<641, 256, 0, stream>>>(X1, X2, P1p, P2p, V01, V02, V12, out);
  k_main<<<1088, 256, 0, stream>>>(X0, X1, X2, V01, V02, V12, P1p, P2p, out);
}